// Round 11
// baseline (427.015 us; speedup 1.0000x reference)
//
#include <hip/hip_runtime.h>
#include <math.h>

// Problem constants
#define BB   4
#define LL   4096
#define CC   512
#define GG   4
#define HH   16
#define KW   5      // conv kernel / offset range factor
#define GCC  128    // C / G
#define HCC  32     // C / H
#define BGN  (BB*GG)   // 16
#define BHN  (BB*HH)   // 64
#define KSPLIT 16

typedef __attribute__((ext_vector_type(8))) __bf16 bf16x8;
typedef __attribute__((ext_vector_type(4))) float f32x4;

// ---------------------------------------------------------------------------
// bf16 split helpers (manual RNE, no header-struct dependence)
// ---------------------------------------------------------------------------
__device__ __forceinline__ unsigned int f2bf_bits(float f) {
    unsigned int u = __float_as_uint(f);
    return (u + 0x7FFFu + ((u >> 16) & 1u)) >> 16;
}
__device__ __forceinline__ float bfbits2f(unsigned int s) {
    return __uint_as_float(s << 16);
}
__device__ __forceinline__ void split2(float v, unsigned short& h, unsigned short& l) {
    unsigned int hb = f2bf_bits(v);
    float hf = bfbits2f(hb);
    unsigned int lb = f2bf_bits(v - hf);
    h = (unsigned short)hb; l = (unsigned short)lb;
}

__device__ __forceinline__ void gload16(const void* g, void* l) {
    __builtin_amdgcn_global_load_lds(
        (const __attribute__((address_space(1))) void*)g,
        (__attribute__((address_space(3))) void*)l, 16, 0, 0);
}

// ---------------------------------------------------------------------------
// split fp32 -> (bf16 hi, bf16 lo), vectorized x4
// ---------------------------------------------------------------------------
__global__ __launch_bounds__(256) void split_x_kernel(
    const float* __restrict__ in, unsigned short* __restrict__ hi,
    unsigned short* __restrict__ lo, int n4)
{
    int i = blockIdx.x * 256 + threadIdx.x;
    if (i >= n4) return;
    float4 v = ((const float4*)in)[i];
    ushort4 h, l;
    split2(v.x, h.x, l.x); split2(v.y, h.y, l.y);
    split2(v.z, h.z, l.z); split2(v.w, h.w, l.w);
    ((ushort4*)hi)[i] = h;
    ((ushort4*)lo)[i] = l;
}

// 4 weight matrices [512x512] each -> hi/lo segments of 262144 elements
__global__ __launch_bounds__(256) void split_w_kernel(
    const float* __restrict__ W0, const float* __restrict__ W1,
    const float* __restrict__ W2, const float* __restrict__ W3,
    unsigned short* __restrict__ hi, unsigned short* __restrict__ lo)
{
    int w = blockIdx.y;
    const float* W = (w == 0) ? W0 : (w == 1) ? W1 : (w == 2) ? W2 : W3;
    size_t seg4 = (size_t)w * 65536;   // 262144/4
    int i = blockIdx.x * 256 + threadIdx.x;   // x4 elements
    float4 v = ((const float4*)W)[i];
    ushort4 h, l;
    split2(v.x, h.x, l.x); split2(v.y, h.y, l.y);
    split2(v.z, h.z, l.z); split2(v.w, h.w, l.w);
    ((ushort4*)hi)[seg4 + i] = h;
    ((ushort4*)lo)[seg4 + i] = l;
}

// ---------------------------------------------------------------------------
// Split-bf16 MFMA GEMM:  D[b][r][c] = sum_k A[b?][r,k]*B[b?][c,k]
// Round-10b: 128x256 block tile, BK=32, 256 thr = 4 waves, wave tile 128x64.
// Rationale (post-null-x3): per-block-K-step cost measured ~3750cy vs ~1550cy
// MFMA demand -> fixed serialization dominates. Fatter tiles amortize it:
// 96 MFMAs per 24 ds_reads per wave (4:1), FLOP/LDS-byte 48->64, grid halves.
// acc[8][4] f32x4 = 128 VGPR; B-frags resident, A-frags streamed per-fi.
// Single 48KB LDS buffer, 2 barriers/K-step. XOR chunk swizzle kept
// (slot = kblk ^ ((row>>1)&3); row bits 1-2 come only from lane&15 -> the
// verified-0-conflict pattern is preserved for both A and B reads).
// DUAL-SET: blockIdx.y >= ySplit selects second A/bias/out set (k+v merge).
// ---------------------------------------------------------------------------
__global__ __launch_bounds__(256, 2) void gemm_split_mfma(
    const unsigned short* __restrict__ Ahi, const unsigned short* __restrict__ Alo,
    const unsigned short* __restrict__ Ahi2, const unsigned short* __restrict__ Alo2,
    const unsigned short* __restrict__ Bhi, const unsigned short* __restrict__ Blo,
    const float* __restrict__ bias, const float* __restrict__ bias2,
    const float* __restrict__ rpb,
    float* __restrict__ out, float* __restrict__ out2, int ySplit,
    int RA, int RB, int Kd, size_t aStride, size_t bStride, int biasOnCol)
{
    __shared__ unsigned short sAh[4096];   // 128 rows x 32 k
    __shared__ unsigned short sAl[4096];
    __shared__ unsigned short sBh[8192];   // 256 rows x 32 k
    __shared__ unsigned short sBl[8192];   // total 48 KB

    const int b  = blockIdx.z;
    const int c0 = blockIdx.x * 256;

    // set selection (block-uniform)
    int rblk = blockIdx.y;
    const unsigned short* Ah_ = Ahi;
    const unsigned short* Al_ = Alo;
    const float* bias_ = bias;
    const float* rpb_  = nullptr;
    float* out_ = out;
    if (rblk >= ySplit) {
        rblk -= ySplit;
        Ah_ = Ahi2; Al_ = Alo2; bias_ = bias2; out_ = out2; rpb_ = rpb;
    }
    const int r0 = rblk * 128;

    const int tid  = threadIdx.x;
    const int lane = tid & 63;
    const int wv   = tid >> 6;

    // staging: wave wv covers A rows [wv*32, +32) and B rows [wv*64, +64).
    // source chunk pre-swizzled: schunk = c ^ ((srow>>1)&3)
    const int srow   = lane >> 2;
    const int schunk = (lane & 3) ^ ((lane >> 3) & 3);
    const size_t laneA = (size_t)(r0 + wv * 32 + srow) * Kd + (size_t)(schunk * 8);
    const size_t laneB = (size_t)(c0 + wv * 64 + srow) * Kd + (size_t)(schunk * 8);
    const unsigned short* gAh = Ah_ + (size_t)b * aStride + laneA;
    const unsigned short* gAl = Al_ + (size_t)b * aStride + laneA;
    const unsigned short* gBh = Bhi + (size_t)b * bStride + laneB;
    const unsigned short* gBl = Blo + (size_t)b * bStride + laneB;
    const size_t rs16 = (size_t)16 * Kd;
    const int ldsA = wv * 1024;   // 32 rows * 32 u16
    const int ldsB = wv * 2048;   // 64 rows * 32 u16

    // fragment read: slot = kblk ^ ((row>>1)&3); row bits 1-2 from lane&15.
    const int lr = lane & 15;
    const int kx = ((lane >> 4) ^ ((lane >> 1) & 3)) * 8;

    f32x4 acc[8][4];
#pragma unroll
    for (int i = 0; i < 8; ++i)
#pragma unroll
        for (int j = 0; j < 4; ++j) acc[i][j] = (f32x4){0.f, 0.f, 0.f, 0.f};

    for (int k0 = 0; k0 < Kd; k0 += 32) {
        // stage current tile: 12 gload16 per thread-slot
        gload16(gAh + k0,        &sAh[ldsA]);
        gload16(gAh + k0 + rs16, &sAh[ldsA + 512]);
        gload16(gAl + k0,        &sAl[ldsA]);
        gload16(gAl + k0 + rs16, &sAl[ldsA + 512]);
        gload16(gBh + k0,            &sBh[ldsB]);
        gload16(gBh + k0 + rs16,     &sBh[ldsB + 512]);
        gload16(gBh + k0 + 2 * rs16, &sBh[ldsB + 1024]);
        gload16(gBh + k0 + 3 * rs16, &sBh[ldsB + 1536]);
        gload16(gBl + k0,            &sBl[ldsB]);
        gload16(gBl + k0 + rs16,     &sBl[ldsB + 512]);
        gload16(gBl + k0 + 2 * rs16, &sBl[ldsB + 1024]);
        gload16(gBl + k0 + 3 * rs16, &sBl[ldsB + 1536]);
        __syncthreads();   // drains vmcnt -> tile resident

        // B fragments resident (wave's own 64-col strip)
        bf16x8 bhf[4], blf[4];
#pragma unroll
        for (int j = 0; j < 4; ++j) {
            const int bo = (wv * 64 + j * 16 + lr) * 32 + kx;
            bhf[j] = *(const bf16x8*)(sBh + bo);
            blf[j] = *(const bf16x8*)(sBl + bo);
        }
        // A fragments streamed: 2 ds_reads feed 12 MFMAs
#pragma unroll
        for (int fi = 0; fi < 8; ++fi) {
            const int ao = (fi * 16 + lr) * 32 + kx;
            bf16x8 ahf = *(const bf16x8*)(sAh + ao);
            bf16x8 alf = *(const bf16x8*)(sAl + ao);
#pragma unroll
            for (int j = 0; j < 4; ++j) {
                acc[fi][j] = __builtin_amdgcn_mfma_f32_16x16x32_bf16(ahf, bhf[j], acc[fi][j], 0, 0, 0);
                acc[fi][j] = __builtin_amdgcn_mfma_f32_16x16x32_bf16(alf, bhf[j], acc[fi][j], 0, 0, 0);
                acc[fi][j] = __builtin_amdgcn_mfma_f32_16x16x32_bf16(ahf, blf[j], acc[fi][j], 0, 0, 0);
            }
        }
        __syncthreads();   // all waves done reading before next stage
    }

    // epilogue: C/D layout col=lane&15, row=(lane>>4)*4+reg  [m89 verified]
    const int lg4 = (lane >> 4) * 4;
    float bcol[4];
#pragma unroll
    for (int fj = 0; fj < 4; ++fj)
        bcol[fj] = biasOnCol ? bias_[c0 + wv * 64 + fj * 16 + lr] : 0.f;

#pragma unroll
    for (int fi = 0; fi < 8; ++fi) {
#pragma unroll
        for (int reg = 0; reg < 4; ++reg) {
            const int r = r0 + fi * 16 + lg4 + reg;
            const float br = biasOnCol ? 0.f : bias_[r];
            float* orow = out_ + ((size_t)b * RA + r) * RB + c0;
            const float* prow = rpb_ ? (rpb_ + (size_t)r * RB + c0) : nullptr;
#pragma unroll
            for (int fj = 0; fj < 4; ++fj) {
                const int c = wv * 64 + fj * 16 + lr;
                float val = acc[fi][fj][reg] + br + bcol[fj];
                if (prow) val += prow[c];
                orow[c] = val;
            }
        }
    }
}

// ---------------------------------------------------------------------------
// Fuse the two offset convs (linear, no activation between)
// ---------------------------------------------------------------------------
__global__ void comb_weights(const float* __restrict__ Woff1, const float* __restrict__ boff1,
                             const float* __restrict__ Woff2, const float* __restrict__ boff2,
                             float* __restrict__ wc)
{
    int idx = blockIdx.x * 256 + threadIdx.x;
    if (idx < GCC * KW) {
        int cp = idx / KW, t = idx - cp * KW;
        float s = 0.f;
        for (int c = 0; c < GCC; ++c)
            s = fmaf(Woff2[c], Woff1[((size_t)c * GCC + cp) * KW + t], s);
        wc[idx] = s;
    } else if (idx == GCC * KW) {
        float s = boff2[0];
        for (int c = 0; c < GCC; ++c) s = fmaf(Woff2[c], boff1[c], s);
        wc[idx] = s;
    } else if (idx == GCC * KW + 1) {
        wc[idx] = boff2[0];
    }
}

// ---------------------------------------------------------------------------
// Offsets stage 1: channel-split conv partials.
// ---------------------------------------------------------------------------
#define OLT 128
__global__ __launch_bounds__(128) void offsets_part_kernel(
    const float* __restrict__ q, const float* __restrict__ wc,
    float* __restrict__ part)
{
    __shared__ float sq[32][140];   // cols 0..135 used; pos = l0-8+col
    __shared__ float sw[32 * KW];

    const int l0 = blockIdx.x * OLT;
    const int bg = blockIdx.y;
    const int cg = blockIdx.z;
    const int tid = threadIdx.x;

    const float* qb = q + ((size_t)bg * GCC + cg * 32) * LL;

    for (int i = tid; i < 32 * KW; i += 128) sw[i] = wc[cg * 32 * KW + i];

    {
        const int row = tid >> 2;
        const int l4  = tid & 3;
        const float* qrow = qb + (size_t)row * LL + l0 - 8;
        for (int j = l4; j < 34; j += 4) {
            int idx = j * 4;
            float4 v;
            if (l0 - 8 + idx >= 0) v = *(const float4*)(qrow + idx);
            else v = make_float4(0.f, 0.f, 0.f, 0.f);
            *(float4*)&sq[row][idx] = v;
        }
    }
    __syncthreads();

    const int li = tid;
    float acc = 0.f;
#pragma unroll
    for (int cp = 0; cp < 32; ++cp) {
        const float* r  = &sq[cp][li + 4];
        const float* wr = &sw[cp * KW];
        acc = fmaf(wr[0], r[0], acc);
        acc = fmaf(wr[1], r[1], acc);
        acc = fmaf(wr[2], r[2], acc);
        acc = fmaf(wr[3], r[3], acc);
        acc = fmaf(wr[4], r[4], acc);
    }
    part[((size_t)cg * BGN + bg) * LL + l0 + li] = acc;
}

// ---------------------------------------------------------------------------
// Offsets stage 2: combine partials, bias/padding cases, tanh -> iy
// ---------------------------------------------------------------------------
__global__ __launch_bounds__(256) void offsets_finish_kernel(
    const float* __restrict__ part, const float* __restrict__ wc,
    float* __restrict__ offv)
{
    int i = blockIdx.x * 256 + threadIdx.x;    // over BGN*LL
    int bg = i >> 12;
    int l  = i & (LL - 1);
    float acc;
    if (l < 2) {
        acc = wc[GCC * KW + 1];                 // conv1 zero-padding region
    } else {
        acc = wc[GCC * KW]
            + part[((size_t)0 * BGN + bg) * LL + l]
            + part[((size_t)1 * BGN + bg) * LL + l]
            + part[((size_t)2 * BGN + bg) * LL + l]
            + part[((size_t)3 * BGN + bg) * LL + l];
    }
    float off = tanhf(acc) * (float)KW;
    float vg  = (float)l + off;
    float iy  = vg * ((float)LL / (float)(LL + 2 * (KW / 2) - 1)) - 0.5f;
    offv[(size_t)bg * LL + l] = iy;
}

// ---------------------------------------------------------------------------
// Bilinear gather -> xs in [B, L, C] layout, written as bf16 hi/lo pair
// ---------------------------------------------------------------------------
__global__ __launch_bounds__(256) void gather_kernel(
    const float* __restrict__ x, const float* __restrict__ offv,
    unsigned short* __restrict__ xshi, unsigned short* __restrict__ xslo)
{
    int bg = blockIdx.y;
    int b = bg >> 2, g = bg & 3;
    int l  = blockIdx.x * 8 + (threadIdx.x >> 5);
    int d4 = (threadIdx.x & 31) * 4;

    float iy = offv[(size_t)bg * LL + l];
    float fi = floorf(iy);
    float w1 = iy - fi;
    int i0 = (int)fi;
    int i1 = i0 + 1;

    const float* xb = x + (size_t)b * LL * CC + (size_t)g * GCC + d4;
    float4 v0 = make_float4(0.f, 0.f, 0.f, 0.f);
    float4 v1 = make_float4(0.f, 0.f, 0.f, 0.f);
    if (i0 >= 0 && i0 < LL) v0 = *(const float4*)(xb + (size_t)i0 * CC);
    if (i1 >= 0 && i1 < LL) v1 = *(const float4*)(xb + (size_t)i1 * CC);
    float w0 = 1.f - w1;
    float4 r = make_float4(v0.x * w0 + v1.x * w1, v0.y * w0 + v1.y * w1,
                           v0.z * w0 + v1.z * w1, v0.w * w0 + v1.w * w1);
    size_t o = ((size_t)b * LL + l) * CC + (size_t)g * GCC + d4;
    ushort4 h, lo4;
    split2(r.x, h.x, lo4.x); split2(r.y, h.y, lo4.y);
    split2(r.z, h.z, lo4.z); split2(r.w, h.w, lo4.w);
    *(ushort4*)(xshi + o) = h;
    *(ushort4*)(xslo + o) = lo4;
}

// ---------------------------------------------------------------------------
// Attention logits, split-K (fp32 vector; small op)
// ---------------------------------------------------------------------------
__global__ __launch_bounds__(64) void qk_logits(
    const float* __restrict__ q, const float* __restrict__ k,
    float* __restrict__ part)
{
    int ks = blockIdx.x, bh = blockIdx.y;
    int b = bh >> 4, h = bh & 15;
    int lane = threadIdx.x;
    int ti = lane >> 3, tj = lane & 7;
    const float* qb = q + ((size_t)b * CC + h * HCC + ti * 4) * LL;
    const float* kb = k + ((size_t)b * CC + h * HCC + tj * 4) * LL;

    float acc[4][4];
#pragma unroll
    for (int i = 0; i < 4; ++i)
#pragma unroll
        for (int j = 0; j < 4; ++j) acc[i][j] = 0.f;

    const int chunk = LL / KSPLIT;
    int l0 = ks * chunk;
    for (int l = l0; l < l0 + chunk; l += 8) {
        float4 qa[4][2], kv[4][2];
#pragma unroll
        for (int p = 0; p < 4; ++p) {
            qa[p][0] = *(const float4*)(qb + (size_t)p * LL + l);
            qa[p][1] = *(const float4*)(qb + (size_t)p * LL + l + 4);
            kv[p][0] = *(const float4*)(kb + (size_t)p * LL + l);
            kv[p][1] = *(const float4*)(kb + (size_t)p * LL + l + 4);
        }
#pragma unroll
        for (int i = 0; i < 4; ++i)
#pragma unroll
            for (int j = 0; j < 4; ++j) {
                float s = acc[i][j];
                s = fmaf(qa[i][0].x, kv[j][0].x, s);
                s = fmaf(qa[i][0].y, kv[j][0].y, s);
                s = fmaf(qa[i][0].z, kv[j][0].z, s);
                s = fmaf(qa[i][0].w, kv[j][0].w, s);
                s = fmaf(qa[i][1].x, kv[j][1].x, s);
                s = fmaf(qa[i][1].y, kv[j][1].y, s);
                s = fmaf(qa[i][1].z, kv[j][1].z, s);
                s = fmaf(qa[i][1].w, kv[j][1].w, s);
                acc[i][j] = s;
            }
    }
#pragma unroll
    for (int i = 0; i < 4; ++i)
#pragma unroll
        for (int j = 0; j < 4; ++j)
            part[(((size_t)bh * KSPLIT + ks) * HCC + ti * 4 + i) * HCC + tj * 4 + j] = acc[i][j];
}

__global__ __launch_bounds__(64) void softmax_kernel(
    const float* __restrict__ part, float* __restrict__ attn)
{
    int bh = blockIdx.x;
    int i = threadIdx.x;
    if (i >= HCC) return;
    const float SCALE = 0.044194173824159216f;  // 512^-0.5

    float lg[HCC];
    float mx = -1e30f;
#pragma unroll
    for (int j = 0; j < HCC; ++j) {
        float s = 0.f;
        for (int ks = 0; ks < KSPLIT; ++ks)
            s += part[(((size_t)bh * KSPLIT + ks) * HCC + i) * HCC + j];
        s *= SCALE;
        lg[j] = s;
        mx = fmaxf(mx, s);
    }
    float sum = 0.f;
#pragma unroll
    for (int j = 0; j < HCC; ++j) {
        float e = expf(lg[j] - mx);
        lg[j] = e;
        sum += e;
    }
    float inv = 1.f / sum;
#pragma unroll
    for (int j = 0; j < HCC; ++j)
        attn[((size_t)bh * HCC + i) * HCC + j] = lg[j] * inv;
}

// ---------------------------------------------------------------------------
// o[bh,i,l] = sum_j attn[i,j]*v[bh,j,l], -> final [B,L,C] layout as bf16 pair
// ---------------------------------------------------------------------------
__global__ __launch_bounds__(256) void attn_v_kernel(
    const float* __restrict__ attn, const float* __restrict__ v,
    unsigned short* __restrict__ ohi, unsigned short* __restrict__ olo)
{
    int bh = blockIdx.y;
    int b = bh >> 4, h = bh & 15;
    int tid = threadIdx.x;
    int i = tid >> 3, lsub = tid & 7;

    float arow[HCC];
#pragma unroll
    for (int j = 0; j < HCC; ++j)
        arow[j] = attn[((size_t)bh * HCC + i) * HCC + j];

    const float* vb = v + ((size_t)b * CC + h * HCC) * LL;
    __shared__ float os[HCC][65];

    for (int l0 = blockIdx.x * 512; l0 < blockIdx.x * 512 + 512; l0 += 64) {
        int lbase = l0 + lsub * 8;
        float4 a0 = make_float4(0.f, 0.f, 0.f, 0.f);
        float4 a1 = make_float4(0.f, 0.f, 0.f, 0.f);
#pragma unroll 8
        for (int j = 0; j < HCC; ++j) {
            float aw = arow[j];
            float4 v0 = *(const float4*)(vb + (size_t)j * LL + lbase);
            float4 v1 = *(const float4*)(vb + (size_t)j * LL + lbase + 4);
            a0.x = fmaf(aw, v0.x, a0.x); a0.y = fmaf(aw, v0.y, a0.y);
            a0.z = fmaf(aw, v0.z, a0.z); a0.w = fmaf(aw, v0.w, a0.w);
            a1.x = fmaf(aw, v1.x, a1.x); a1.y = fmaf(aw, v1.y, a1.y);
            a1.z = fmaf(aw, v1.z, a1.z); a1.w = fmaf(aw, v1.w, a1.w);
        }
        os[i][lsub*8+0] = a0.x; os[i][lsub*8+1] = a0.y;
        os[i][lsub*8+2] = a0.z; os[i][lsub*8+3] = a0.w;
        os[i][lsub*8+4] = a1.x; os[i][lsub*8+5] = a1.y;
        os[i][lsub*8+6] = a1.z; os[i][lsub*8+7] = a1.w;
        __syncthreads();
        int i2 = tid & 31, lw = tid >> 5;
#pragma unroll
        for (int c = 0; c < 8; ++c) {
            int ll = lw * 8 + c;
            float val = os[i2][ll];
            unsigned short hbits, lbits;
            split2(val, hbits, lbits);
            size_t oidx = ((size_t)b * LL + l0 + ll) * CC + h * HCC + i2;
            ohi[oidx] = hbits;
            olo[oidx] = lbits;
        }
        __syncthreads();
    }
}

// ---------------------------------------------------------------------------
extern "C" void kernel_launch(void* const* d_in, const int* in_sizes, int n_in,
                              void* d_out, int out_size, void* d_ws, size_t ws_size,
                              hipStream_t stream)
{
    (void)in_sizes; (void)n_in; (void)out_size; (void)ws_size;
    const float* x     = (const float*)d_in[0];
    const float* Wq    = (const float*)d_in[1];
    const float* bq    = (const float*)d_in[2];
    const float* Wk    = (const float*)d_in[3];
    const float* bk    = (const float*)d_in[4];
    const float* Wv    = (const float*)d_in[5];
    const float* bv    = (const float*)d_in[6];
    const float* Woff1 = (const float*)d_in[7];
    const float* boff1 = (const float*)d_in[8];
    const float* Woff2 = (const float*)d_in[9];
    const float* boff2 = (const float*)d_in[10];
    const float* rpb   = (const float*)d_in[11];
    const float* Wout  = (const float*)d_in[12];
    const float* bout  = (const float*)d_in[13];
    float* out = (float*)d_out;

    float* ws = (float*)d_ws;
    float* q    = ws;                          // [B,C,L]  8,388,608 f
    float* kbuf = ws + 8388608;                // [B,C,L]  8,388,608 f
    float* vbuf = ws + 16777216;               // [B,C,L]  8,388,608 f
    unsigned short* dhi = (unsigned short*)(ws + 25165824);   // 8,388,608 u16
    unsigned short* dlo = (unsigned short*)(ws + 25165824 + 4194304);
    unsigned short* whi = (unsigned short*)(ws + 33554432);   // 4x262144 u16
    unsigned short* wlo = (unsigned short*)(ws + 33554432 + 524288);
    float* offv = ws + 34603008;               // [BG,L]  65,536
    float* wcmb = ws + 34668544;               // 1,024
    float* part = ws + 34669568;               // [64,16,32,32] 1,048,576 (also offsets partials)
    float* attn = ws + 35718144;               // [64,32,32] 65,536

    const size_t NK = (size_t)LL * CC;   // per-batch activation elems
    const int NOSPLIT = 1 << 20;

    comb_weights<<<dim3(3), dim3(256), 0, stream>>>(Woff1, boff1, Woff2, boff2, wcmb);
    split_w_kernel<<<dim3(256, 4), dim3(256), 0, stream>>>(Wq, Wk, Wv, Wout, whi, wlo);
    split_x_kernel<<<dim3(8192), dim3(256), 0, stream>>>(x, dhi, dlo, 2097152);

    // q = Wq @ x^T -> [B,C,L]   (block 128x256: grid 16 x 4 x 4 = 256)
    gemm_split_mfma<<<dim3(16, 4, 4), dim3(256), 0, stream>>>(
        whi + 0 * 262144, wlo + 0 * 262144, whi, wlo, dhi, dlo,
        bq, bq, nullptr, q, q, NOSPLIT,
        CC, LL, CC, 0, NK, 0);

    // offset prediction (two-stage, parallel)
    offsets_part_kernel<<<dim3(32, 16, 4), dim3(128), 0, stream>>>(q, wcmb, part);
    offsets_finish_kernel<<<dim3(256), dim3(256), 0, stream>>>(part, wcmb, offv);
    gather_kernel<<<dim3(512, 16), dim3(256), 0, stream>>>(x, offv, dhi, dlo);

    // k = Wk @ xs^T ; v = Wv @ xs^T + rpb  -- MERGED: grid 16 x 8 x 4 = 512
    gemm_split_mfma<<<dim3(16, 8, 4), dim3(256), 0, stream>>>(
        whi + 1 * 262144, wlo + 1 * 262144,        // set1: Wk
        whi + 2 * 262144, wlo + 2 * 262144,        // set2: Wv
        dhi, dlo, bk, bv, rpb, kbuf, vbuf, 4,
        CC, LL, CC, 0, NK, 0);

    qk_logits<<<dim3(KSPLIT, BHN), dim3(64), 0, stream>>>(q, kbuf, part);
    softmax_kernel<<<dim3(BHN), dim3(64), 0, stream>>>(part, attn);
    attn_v_kernel<<<dim3(8, BHN), dim3(256), 0, stream>>>(attn, vbuf, dhi, dlo);

    // out = o @ Wout^T + bout -> [B,L,C]  (grid 2 x 32 x 4 = 256)
    gemm_split_mfma<<<dim3(2, 32, 4), dim3(256), 0, stream>>>(
        dhi, dlo, dhi, dlo, whi + 3 * 262144, wlo + 3 * 262144,
        bout, bout, nullptr, out, out, NOSPLIT,
        LL, CC, CC, NK, 0, 1);
}